// Round 12
// baseline (380.808 us; speedup 1.0000x reference)
//
#include <hip/hip_runtime.h>

// ---------------------------------------------------------------------------
// GAT 2-layer forward on MI355X. Round 12:
//  - gemm_k2048_db: conv2 projection with TRUE double-buffered staging using
//    manual `s_waitcnt vmcnt(N)` + raw s_barrier (prefetch for k+1 stays in
//    flight across the barrier; __syncthreads cannot express this). Tile
//    32x128, 2x625 blocks, 40KB LDS -> 4 blocks/CU (occupancy cap). att2 dots
//    become partial + atomicAdd (a_s2/a_d2 pre-zeroed).
//  - alpha2 fused into agg2 (round-5 proven online-softmax wave kernel).
//  Everything else identical to round 11 (best: 375.9 us).
// ---------------------------------------------------------------------------

#define NEG_SLOPE 0.2f

typedef __attribute__((ext_vector_type(8))) short bf16x8;
typedef __attribute__((ext_vector_type(4))) float f32x4;

__device__ __forceinline__ float bf2f(unsigned short u) {
  return __uint_as_float(((unsigned)u) << 16);
}
__device__ __forceinline__ unsigned short f2bf(float f) {
  unsigned u = __float_as_uint(f);
  u += 0x7fffu + ((u >> 16) & 1u);   // round-to-nearest-even
  return (unsigned short)(u >> 16);
}

__device__ __forceinline__ void async_copy16(const void* g, void* l) {
  __builtin_amdgcn_global_load_lds(
      (const __attribute__((address_space(1))) unsigned int*)g,
      (__attribute__((address_space(3))) unsigned int*)l, 16, 0, 0);
}

// ---------------------------------------------------------------------------
// prep: fold W_node/W_col halves, convert MFMA operands to bf16, and compute
// v_s1/v_d1 = att1 @ W1 (per-head 256-dots) as an extra index range.
__global__ void prep(const float* __restrict__ Wn, const float* __restrict__ Wc,
                     const float* __restrict__ W1, const float* __restrict__ W2,
                     const float* __restrict__ Wout,
                     const float* __restrict__ cons, const float* __restrict__ cols,
                     const float* __restrict__ att_s1, const float* __restrict__ att_d1,
                     unsigned short* __restrict__ Wn_b, unsigned short* __restrict__ Wc_b,
                     unsigned short* __restrict__ W1b, unsigned short* __restrict__ W2b,
                     unsigned short* __restrict__ Woutb,
                     unsigned short* __restrict__ consb, unsigned short* __restrict__ colsb,
                     float* __restrict__ v_s1, float* __restrict__ v_d1,
                     int n_cons, int n_cols) {
  const int S0 = 256 * 64;
  const int S1 = 256 * 128;
  const int S2 = 2048 * 256;
  const int S3 = 256 * 2048;
  const int S4 = 128 * 256;
  const int S5 = 2048;                 // v1 (h,k) items
  int total = S0 + S1 + S2 + S3 + S4 + n_cons + n_cols + S5;
  for (int idx = blockIdx.x * 256 + threadIdx.x; idx < total; idx += gridDim.x * 256) {
    int i = idx;
    if (i < S0) { int o = i >> 6, j = i & 63;
      Wn_b[i] = f2bf(Wn[o * 128 + j] + Wn[o * 128 + 64 + j]); continue; }
    i -= S0;
    if (i < S1) { int o = i >> 7, j = i & 127;
      Wc_b[i] = f2bf(Wc[o * 256 + j] + Wc[o * 256 + 128 + j]); continue; }
    i -= S1;
    if (i < S2) { W1b[i] = f2bf(W1[i]); continue; }
    i -= S2;
    if (i < S3) { W2b[i] = f2bf(W2[i]); continue; }
    i -= S3;
    if (i < S4) { Woutb[i] = f2bf(Wout[i]); continue; }
    i -= S4;
    if (i < n_cons) { consb[i] = f2bf(cons[i]); continue; }
    i -= n_cons;
    if (i < n_cols) { colsb[i] = f2bf(cols[i]); continue; }
    i -= n_cols;
    { // v1: i in [0,2048), h = i>>8, k = i&255
      int h = i >> 8, k = i & 255;
      const float* Wrow = W1 + (size_t)h * 256 * 256 + k;
      const float* as = att_s1 + h * 256;
      const float* ad = att_d1 + h * 256;
      float s = 0.f, d = 0.f;
      for (int c = 0; c < 256; ++c) {
        float w = Wrow[(size_t)c * 256];
        s += as[c] * w;
        d += ad[c] * w;
      }
      v_s1[i] = s; v_d1[i] = d;
    }
  }
}

// ---------------------------------------------------------------------------
// a_s1[n,h] = xb[n,:] . v_s[h,:]  (thread per node; v in LDS, broadcast reads)
__global__ __launch_bounds__(256) void a1_dots(const unsigned short* __restrict__ xb,
                                               const float* __restrict__ v_s,
                                               const float* __restrict__ v_d,
                                               float* __restrict__ a_s,
                                               float* __restrict__ a_d, int N) {
  __shared__ float vs[2048], vd[2048];
  for (int i = threadIdx.x; i < 2048; i += 256) { vs[i] = v_s[i]; vd[i] = v_d[i]; }
  __syncthreads();
  int n = blockIdx.x * 256 + threadIdx.x;
  if (n >= N) return;
  const unsigned short* row = xb + (size_t)n * 256;
  float s[8] = {}, d[8] = {};
  for (int c = 0; c < 256; c += 8) {
    bf16x8 xv = *(const bf16x8*)(row + c);
    float xf[8];
#pragma unroll
    for (int i = 0; i < 8; ++i) xf[i] = bf2f(((const unsigned short*)&xv)[i]);
#pragma unroll
    for (int h = 0; h < 8; ++h)
#pragma unroll
      for (int i = 0; i < 8; ++i) {
        s[h] += xf[i] * vs[h * 256 + c + i];
        d[h] += xf[i] * vd[h * 256 + c + i];
      }
  }
#pragma unroll
  for (int h = 0; h < 8; ++h) { a_s[n * 8 + h] = s[h]; a_d[n * 8 + h] = d[h]; }
}

// ---------------------------------------------------------------------------
// bf16 MFMA GEMM, B^T layout: C[m,n] = sum_k A[m, koff+k] * W[n,k] (+bias,relu).
// 512 threads, 8 waves; wave w owns rows [(w&3)*32,+32) x cols [(w>>2)*64,+64)
// of the 128x128 tile. XOR-swizzled staging, coalesced bf16 epilogue via LDS.
template <bool C_BF16, bool BIAS, bool RELU, bool BDIAG>
__global__ __launch_bounds__(512) void gemm_mfma_bt(const unsigned short* __restrict__ A,
                                                    const unsigned short* __restrict__ W,
                                                    const float* __restrict__ bias,
                                                    void* __restrict__ Cv,
                                                    int M, int K, int Nout, int lda) {
  __shared__ short smem[2 * 128 * 64];   // sA | sB, reused as C-tile in epilogue
  short* sA = smem;
  short* sB = smem + 128 * 64;
  float* Cf = (float*)Cv;
  unsigned short* Cb = (unsigned short*)Cv;

  const int tid = threadIdx.x;
  const int lane = tid & 63, w = tid >> 6;
  const int m0 = blockIdx.y * 128, n0 = blockIdx.x * 128;
  const int koff = BDIAG ? (n0 >> 8) << 8 : 0;
  const int wm = (w & 3) * 32, wn = (w >> 2) * 64;
  const int fr = lane & 15;
  const int frs = fr & 7;
  const int quad = lane >> 4;

  f32x4 acc[2][4];
#pragma unroll
  for (int i = 0; i < 2; ++i)
#pragma unroll
    for (int j = 0; j < 4; ++j) acc[i][j] = (f32x4){0.f, 0.f, 0.f, 0.f};

  for (int k0 = 0; k0 < K; k0 += 64) {
#pragma unroll
    for (int i = 0; i < 2; ++i) {
      int c = i * 512 + tid;
      int row = c >> 3, kc = c & 7;
      int kcs = kc ^ (row & 7);            // XOR swizzle (global side)
      int grow = m0 + row;
      if (grow >= M) grow = M - 1;
      async_copy16(A + (size_t)grow * lda + koff + k0 + kcs * 8, &sA[(i * 512 + w * 64) * 8]);
    }
#pragma unroll
    for (int i = 0; i < 2; ++i) {
      int c = i * 512 + tid;
      int row = c >> 3, kc = c & 7;
      int kcs = kc ^ (row & 7);
      async_copy16(W + (size_t)(n0 + row) * K + k0 + kcs * 8, &sB[(i * 512 + w * 64) * 8]);
    }
    __syncthreads();

#pragma unroll
    for (int ks = 0; ks < 2; ++ks) {
      bf16x8 af[2], bfr[4];
#pragma unroll
      for (int mi = 0; mi < 2; ++mi) {
        int row = wm + mi * 16 + fr;
        af[mi] = *(const bf16x8*)&sA[(row * 8 + ((ks * 4 + quad) ^ frs)) * 8];
      }
#pragma unroll
      for (int ni = 0; ni < 4; ++ni) {
        int row = wn + ni * 16 + fr;
        bfr[ni] = *(const bf16x8*)&sB[(row * 8 + ((ks * 4 + quad) ^ frs)) * 8];
      }
#pragma unroll
      for (int mi = 0; mi < 2; ++mi)
#pragma unroll
        for (int ni = 0; ni < 4; ++ni)
          acc[mi][ni] = __builtin_amdgcn_mfma_f32_16x16x32_bf16(
              af[mi], bfr[ni], acc[mi][ni], 0, 0, 0);
    }
    __syncthreads();
  }

  if (C_BF16) {
    unsigned short* hsh = (unsigned short*)smem;    // 128*128 u16 = 32 KB
#pragma unroll
    for (int mi = 0; mi < 2; ++mi)
#pragma unroll
      for (int ni = 0; ni < 4; ++ni) {
        int col = wn + ni * 16 + fr;
        float bv = BIAS ? bias[n0 + col] : 0.f;
        f32x4 v = acc[mi][ni];
#pragma unroll
        for (int r = 0; r < 4; ++r) {
          int row = wm + mi * 16 + quad * 4 + r;
          float x = v[r] + bv;
          if (RELU) x = fmaxf(x, 0.f);
          hsh[row * 128 + (col ^ (((row >> 2) & 3) << 5))] = f2bf(x);
        }
      }
    __syncthreads();
#pragma unroll
    for (int i = 0; i < 4; ++i) {
      int slot = i * 512 + tid;          // 0..2047 = 128 rows x 16 col-groups
      int row = slot >> 4, cg = slot & 15;
      int colbase = cg * 8;
      bf16x8 val = *(const bf16x8*)&hsh[row * 128 + (colbase ^ (((row >> 2) & 3) << 5))];
      int grow = m0 + row;
      if (grow < M)
        *(bf16x8*)(Cb + (size_t)grow * Nout + n0 + colbase) = val;
    }
  } else {
#pragma unroll
    for (int mi = 0; mi < 2; ++mi)
#pragma unroll
      for (int ni = 0; ni < 4; ++ni) {
        int col = n0 + wn + ni * 16 + fr;
        float bv = BIAS ? bias[col] : 0.f;
        f32x4 v = acc[mi][ni];
#pragma unroll
        for (int r = 0; r < 4; ++r) {
          int row = m0 + wm + mi * 16 + quad * 4 + r;
          if (row < M) {
            float x = v[r] + bv;
            if (RELU) x = fmaxf(x, 0.f);
            Cf[(size_t)row * Nout + col] = x;
          }
        }
      }
  }
}

// ---------------------------------------------------------------------------
// conv2 projection GEMM, DOUBLE-BUFFERED: h2[M,256] = A[M,2048] * W[256,2048]^T.
// Tile 32 rows x 128 cols; grid (2, M/32). 512 thr / 8 waves, wave w owns
// cols [w*16,+16) (acc 2x1). Prefetch k+1 into the other LDS buffer, then
// wait only the PREVIOUS iteration's loads (manual vmcnt) + raw s_barrier —
// the prefetch stays in flight across the barrier.
// Fused att2 dots are PARTIAL (128 cols) -> atomicAdd into pre-zeroed a_s/a_d.
__global__ __launch_bounds__(512) void gemm_k2048_db(const unsigned short* __restrict__ A,
                                                     const unsigned short* __restrict__ W,
                                                     unsigned short* __restrict__ C,
                                                     const float* __restrict__ att_s,
                                                     const float* __restrict__ att_d,
                                                     float* __restrict__ a_s,
                                                     float* __restrict__ a_d,
                                                     int M, int K) {
  __shared__ short sA[2][32 * 64];     // 8 KB
  __shared__ short sB[2][128 * 64];    // 32 KB
  const int tid = threadIdx.x;
  const int lane = tid & 63, w = tid >> 6;   // w in 0..7
  const int m0 = blockIdx.y * 32;
  const int n0 = blockIdx.x * 128;
  const int fr = lane & 15, quad = lane >> 4;
  const int frs = fr & 7;
  const int wn = w * 16;
  const int NT = K >> 6;

  const int arow = tid >> 3;
  const int akc = (tid & 7) ^ (arow & 7);
  int aclamp = m0 + arow; if (aclamp >= M) aclamp = M - 1;

  f32x4 acc0 = (f32x4){0.f, 0.f, 0.f, 0.f};
  f32x4 acc1 = (f32x4){0.f, 0.f, 0.f, 0.f};

  // ---- stage(kt, buf): A tile 32x64 (waves 0..3), B tile 128x64 (2/thread)
#define STAGE(KT, BUF)                                                         \
  do {                                                                         \
    int k0_ = (KT) << 6;                                                       \
    if (w < 4)                                                                 \
      async_copy16(A + (size_t)aclamp * K + k0_ + akc * 8,                     \
                   &sA[BUF][(w * 64) * 8]);                                    \
    _Pragma("unroll")                                                          \
    for (int i_ = 0; i_ < 2; ++i_) {                                           \
      int c_ = i_ * 512 + tid;                                                 \
      int row_ = c_ >> 3, kc_ = (c_ & 7) ^ (row_ & 7);                         \
      async_copy16(W + (size_t)(n0 + row_) * K + k0_ + kc_ * 8,                \
                   &sB[BUF][(i_ * 512 + w * 64) * 8]);                         \
    }                                                                          \
  } while (0)

  STAGE(0, 0);
  for (int kt = 0; kt < NT; ++kt) {
    int cur = kt & 1;
    if (kt + 1 < NT) {
      STAGE(kt + 1, cur ^ 1);
      // wait only the PREVIOUS stage's loads (w<4 issued 3/stage, else 2)
      if (w < 4) __builtin_amdgcn_s_waitcnt(0x0F73);   // vmcnt(3)
      else       __builtin_amdgcn_s_waitcnt(0x0F72);   // vmcnt(2)
    } else {
      __builtin_amdgcn_s_waitcnt(0x0F70);              // vmcnt(0)
    }
    __builtin_amdgcn_s_barrier();
#pragma unroll
    for (int ks = 0; ks < 2; ++ks) {
      int sw = (ks * 4 + quad) ^ frs;
      bf16x8 af0 = *(const bf16x8*)&sA[cur][((fr) * 8 + sw) * 8];
      bf16x8 af1 = *(const bf16x8*)&sA[cur][((16 + fr) * 8 + sw) * 8];
      bf16x8 bf0 = *(const bf16x8*)&sB[cur][((wn + fr) * 8 + sw) * 8];
      acc0 = __builtin_amdgcn_mfma_f32_16x16x32_bf16(af0, bf0, acc0, 0, 0, 0);
      acc1 = __builtin_amdgcn_mfma_f32_16x16x32_bf16(af1, bf0, acc1, 0, 0, 0);
    }
    __builtin_amdgcn_s_waitcnt(0xC07F);                // lgkmcnt(0)
    __builtin_amdgcn_s_barrier();
  }
#undef STAGE

  // epilogue: stage 32x128 bf16 tile (reuse sA = exactly 8 KB), coalesced
  // stores + partial att dots via atomicAdd.
  unsigned short* hsh = (unsigned short*)sA;
#pragma unroll
  for (int mi = 0; mi < 2; ++mi) {
    f32x4 v = mi ? acc1 : acc0;
    int col = wn + fr;
#pragma unroll
    for (int r = 0; r < 4; ++r) {
      int row = mi * 16 + quad * 4 + r;
      hsh[row * 128 + col] = f2bf(v[r]);
    }
  }
  __syncthreads();

  {
    int row = tid >> 4, cg = tid & 15;   // 32 rows x 16 col-groups
    int grow = m0 + row;
    if (grow < M)
      *(bf16x8*)(C + (size_t)grow * 256 + n0 + cg * 8) =
          *(const bf16x8*)&hsh[row * 128 + cg * 8];
  }
  {
    int r = tid >> 4;
    int cb = (tid & 15) * 8;
    bf16x8 hv8 = *(const bf16x8*)&hsh[r * 128 + cb];
    const unsigned short* hp = (const unsigned short*)&hv8;
    float s = 0.f, d = 0.f;
#pragma unroll
    for (int i = 0; i < 8; ++i) {
      float hv = bf2f(hp[i]);
      s += hv * att_s[n0 + cb + i];
      d += hv * att_d[n0 + cb + i];
    }
#pragma unroll
    for (int off = 8; off; off >>= 1) {
      s += __shfl_down(s, off);
      d += __shfl_down(d, off);
    }
    if ((tid & 15) == 0 && m0 + r < M) {
      atomicAdd(&a_s[m0 + r], s);
      atomicAdd(&a_d[m0 + r], d);
    }
  }
}

// ---------------------------------------------------------------------------
// Edge materialization + degree counts (fused). int64/int32 auto-detect.
__global__ void build_count(const void* __restrict__ edges_raw, int E, int N,
                            int* __restrict__ esrc, int* __restrict__ edst,
                            int* __restrict__ cnt1, int* __restrict__ cnt2, int E1) {
  const long long* p64 = (const long long*)edges_raw;
  const int* p32 = (const int*)edges_raw;
  bool is64 = true;
#pragma unroll
  for (int i = 0; i < 8; ++i) {
    long long v = p64[i];
    if (v < 0 || v >= N) is64 = false;
  }
  int idx = blockIdx.x * 256 + threadIdx.x;
  if (idx >= E1) return;
  int s, d;
  if (idx < E) {
    if (is64) { s = (int)p64[idx]; d = (int)p64[E + idx]; }
    else      { s = p32[idx];      d = p32[E + idx]; }
  } else {
    s = d = idx - E;
  }
  esrc[idx] = s;
  edst[idx] = d;
  atomicAdd(&cnt1[d], 1);
  atomicAdd(&cnt2[s], 1);
}

// ---------------------------------------------------------------------------
// Shuffle-based single-block scan: 3 barriers per 1024-chunk.
__device__ __forceinline__ void scan_one(const int* __restrict__ cnt,
                                         int* __restrict__ indptr,
                                         int* __restrict__ cur, int N, int* buf) {
  int t = threadIdx.x, lane = t & 63, w = t >> 6;
  int running = 0;
  for (int base = 0; base < N; base += 1024) {
    int v = (base + t < N) ? cnt[base + t] : 0;
    int incl = v;
#pragma unroll
    for (int off = 1; off < 64; off <<= 1) {
      int y = __shfl_up(incl, off);
      if (lane >= off) incl += y;
    }
    if (lane == 63) buf[w] = incl;
    __syncthreads();
    if (t < 16) {
      int x = buf[t];
#pragma unroll
      for (int off = 1; off < 16; off <<= 1) {
        int y = __shfl_up(x, off);
        if (t >= off) x += y;
      }
      buf[t] = x;
    }
    __syncthreads();
    int woff = w ? buf[w - 1] : 0;
    int tot = buf[15];
    if (base + t < N) {
      int excl = running + woff + incl - v;
      indptr[base + t] = excl;
      cur[base + t] = excl;
    }
    running += tot;
    __syncthreads();
  }
  if (t == 0) indptr[N] = running;
  __syncthreads();
}

__global__ __launch_bounds__(1024) void scan2_kernel(const int* cnt1, int* indptr1, int* cur1,
                                                     const int* cnt2, int* indptr2, int* cur2,
                                                     int N) {
  __shared__ int buf[16];
  scan_one(cnt1, indptr1, cur1, N, buf);
  scan_one(cnt2, indptr2, cur2, N, buf);
}

// scatter neighbor node-ids directly.
__global__ void scatter_edges(const int* __restrict__ esrc, const int* __restrict__ edst,
                              int* __restrict__ cur1, int* __restrict__ cur2,
                              int* __restrict__ nbr1, int* __restrict__ nbr2, int E1) {
  int e = blockIdx.x * 256 + threadIdx.x;
  if (e >= E1) return;
  int s = esrc[e], d = edst[e];
  int p1 = atomicAdd(&cur1[d], 1);
  nbr1[p1] = s;
  int p2 = atomicAdd(&cur2[s], 1);
  nbr2[p2] = d;
}

// ---------------------------------------------------------------------------
// alpha1: thread-per-dst scalar online softmax (8 heads); writes NORMALIZED
// alpha to CSR slots [slot*8+h].
__global__ __launch_bounds__(256) void alpha1_kernel(const float* __restrict__ a_s,
                                                     const float* __restrict__ a_d,
                                                     const int* __restrict__ indptr,
                                                     const int* __restrict__ nbr,
                                                     float* __restrict__ alpha, int N) {
  int n = blockIdx.x * 256 + threadIdx.x;
  if (n >= N) return;
  int start = indptr[n], end = indptr[n + 1];
  float ad[8];
  *(float4*)&ad[0] = *(const float4*)&a_d[n * 8];
  *(float4*)&ad[4] = *(const float4*)&a_d[n * 8 + 4];
  float m[8], ssum[8];
#pragma unroll
  for (int h = 0; h < 8; ++h) { m[h] = -1e30f; ssum[h] = 0.f; }
  for (int p = start; p < end; ++p) {
    int s = nbr[p];
    float as[8];
    *(float4*)&as[0] = *(const float4*)&a_s[s * 8];
    *(float4*)&as[4] = *(const float4*)&a_s[s * 8 + 4];
#pragma unroll
    for (int h = 0; h < 8; ++h) {
      float e = as[h] + ad[h];
      e = e > 0.f ? e : NEG_SLOPE * e;
      float nm = fmaxf(m[h], e);
      ssum[h] = ssum[h] * __expf(m[h] - nm) + __expf(e - nm);
      m[h] = nm;
    }
  }
  float inv[8];
#pragma unroll
  for (int h = 0; h < 8; ++h) inv[h] = 1.f / (ssum[h] + 1e-16f);
  for (int p = start; p < end; ++p) {
    int s = nbr[p];
    float as[8];
    *(float4*)&as[0] = *(const float4*)&a_s[s * 8];
    *(float4*)&as[4] = *(const float4*)&a_s[s * 8 + 4];
    float av[8];
#pragma unroll
    for (int h = 0; h < 8; ++h) {
      float e = as[h] + ad[h];
      e = e > 0.f ? e : NEG_SLOPE * e;
      av[h] = __expf(e - m[h]) * inv[h];
    }
    *(float4*)&alpha[(size_t)p * 8] = *(const float4*)&av[0];
    *(float4*)&alpha[(size_t)p * 8 + 4] = *(const float4*)&av[4];
  }
}

// ---------------------------------------------------------------------------
// conv1 aggregation, lean: wave-per-dst (4/block), alphas precomputed.
__global__ __launch_bounds__(256) void agg1_kernel(const unsigned short* __restrict__ xb,
                                                   const float* __restrict__ alpha,
                                                   const int* __restrict__ indptr,
                                                   const int* __restrict__ nbr,
                                                   unsigned short* __restrict__ agg,
                                                   int N) {
  __shared__ float al_sh[4][64 * 8];
  const int w = threadIdx.x >> 6, lane = threadIdx.x & 63;
  const int dst = blockIdx.x * 4 + w;
  if (dst >= N) return;
  const int start = indptr[dst];
  const int deg = indptr[dst + 1] - start;
  const int c0 = lane * 4;

  float acc[8][4];
#pragma unroll
  for (int h = 0; h < 8; ++h)
#pragma unroll
    for (int i = 0; i < 4; ++i) acc[h][i] = 0.f;

  for (int base = 0; base < deg; base += 64) {
    int cnt = min(64, deg - base);
    int s = 0;
    if (lane < cnt) {
      int slot = start + base + lane;
      s = nbr[slot];
      f32x4 a0 = *(const f32x4*)&alpha[(size_t)slot * 8];
      f32x4 a1 = *(const f32x4*)&alpha[(size_t)slot * 8 + 4];
      *(f32x4*)&al_sh[w][lane * 8] = a0;
      *(f32x4*)&al_sh[w][lane * 8 + 4] = a1;
    }
    __builtin_amdgcn_wave_barrier();
    for (int j = 0; j < cnt; ++j) {
      int sj = __shfl(s, j);
      f32x4 alo = *(const f32x4*)&al_sh[w][j * 8];
      f32x4 ahi = *(const f32x4*)&al_sh[w][j * 8 + 4];
      ushort4 xv = *(const ushort4*)(xb + (size_t)sj * 256 + c0);
      float x0 = bf2f(xv.x), x1 = bf2f(xv.y), x2 = bf2f(xv.z), x3 = bf2f(xv.w);
#pragma unroll
      for (int h = 0; h < 4; ++h) {
        acc[h][0] += alo[h] * x0; acc[h][1] += alo[h] * x1;
        acc[h][2] += alo[h] * x2; acc[h][3] += alo[h] * x3;
      }
#pragma unroll
      for (int h = 0; h < 4; ++h) {
        acc[h + 4][0] += ahi[h] * x0; acc[h + 4][1] += ahi[h] * x1;
        acc[h + 4][2] += ahi[h] * x2; acc[h + 4][3] += ahi[h] * x3;
      }
    }
    __builtin_amdgcn_wave_barrier();
  }

  unsigned short* op = agg + (size_t)dst * 2048;
#pragma unroll
  for (int h = 0; h < 8; ++h) {
    unsigned short ov[4];
#pragma unroll
    for (int i = 0; i < 4; ++i) ov[i] = f2bf(acc[h][i]);
    *((ushort4*)(op + h * 256 + c0)) = *((const ushort4*)ov);
  }
}

// ---------------------------------------------------------------------------
// conv2 aggregation with FUSED online-softmax alpha (1 head), wave-per-dst,
// dst in [Nc,N) only (round-5 proven structure).
__global__ __launch_bounds__(256) void agg2_fused(const unsigned short* __restrict__ h2,
                                                  const float* __restrict__ a_s,
                                                  const float* __restrict__ a_d,
                                                  const int* __restrict__ indptr,
                                                  const int* __restrict__ nbr,
                                                  const float* __restrict__ b2,
                                                  unsigned short* __restrict__ x3,
                                                  int Nc, int Ncol) {
  const int w = threadIdx.x >> 6, lane = threadIdx.x & 63;
  const int i0 = blockIdx.x * 4 + w;
  if (i0 >= Ncol) return;
  const int dst = Nc + i0;
  const int start = indptr[dst];
  const int deg = indptr[dst + 1] - start;
  const float ad = a_d[dst];
  float run_m = -1e30f, run_s = 0.f;
  float acc[4] = {0.f, 0.f, 0.f, 0.f};
  const int c0 = lane * 4;

  for (int base = 0; base < deg; base += 64) {
    int cnt = min(64, deg - base);
    float ev = -1e30f;
    int s = 0;
    if (lane < cnt) {
      s = nbr[start + base + lane];
      float e = a_s[s] + ad;
      ev = e > 0.f ? e : NEG_SLOPE * e;
    }
    float cm = ev;
#pragma unroll
    for (int off = 32; off; off >>= 1) cm = fmaxf(cm, __shfl_xor(cm, off));
    float nm = fmaxf(run_m, cm);
    float sc = __expf(run_m - nm);
    float e = (lane < cnt) ? __expf(ev - nm) : 0.f;
    float cs = e;
#pragma unroll
    for (int off = 32; off; off >>= 1) cs += __shfl_xor(cs, off);
    run_s = run_s * sc + cs;
    run_m = nm;
#pragma unroll
    for (int i = 0; i < 4; ++i) acc[i] *= sc;
    for (int j = 0; j < cnt; ++j) {
      int sj = __shfl(s, j);
      float al = __shfl(e, j);
      ushort4 hv = *(const ushort4*)(h2 + (size_t)sj * 256 + c0);
      acc[0] += al * bf2f(hv.x);
      acc[1] += al * bf2f(hv.y);
      acc[2] += al * bf2f(hv.z);
      acc[3] += al * bf2f(hv.w);
    }
  }

  float inv = 1.f / (run_s + 1e-16f);
  float4 bv = *(const float4*)&b2[c0];
  unsigned short ov[4];
  ov[0] = f2bf(fmaxf(acc[0] * inv + bv.x, 0.f));
  ov[1] = f2bf(fmaxf(acc[1] * inv + bv.y, 0.f));
  ov[2] = f2bf(fmaxf(acc[2] * inv + bv.z, 0.f));
  ov[3] = f2bf(fmaxf(acc[3] * inv + bv.w, 0.f));
  *((ushort4*)(x3 + (size_t)i0 * 256 + c0)) = *((const ushort4*)ov);
}

// ---------------------------------------------------------------------------
extern "C" void kernel_launch(void* const* d_in, const int* in_sizes, int n_in,
                              void* d_out, int out_size, void* d_ws, size_t ws_size,
                              hipStream_t stream) {
  (void)n_in; (void)out_size; (void)ws_size;
  const float* constraints = (const float*)d_in[0];
  const float* columns     = (const float*)d_in[1];
  const void*  edges       = d_in[2];
  const float* W_node = (const float*)d_in[3];
  const float* b_node = (const float*)d_in[4];
  const float* W_col  = (const float*)d_in[5];
  const float* b_col  = (const float*)d_in[6];
  const float* W1       = (const float*)d_in[7];
  const float* att_src1 = (const float*)d_in[8];
  const float* att_dst1 = (const float*)d_in[9];
  const float* b1       = (const float*)d_in[10];
  const float* W2       = (const float*)d_in[11];
  const float* att_src2 = (const float*)d_in[12];
  const float* att_dst2 = (const float*)d_in[13];
  const float* b2       = (const float*)d_in[14];
  const float* W_out    = (const float*)d_in[15];
  const float* b_out    = (const float*)d_in[16];

  const int Nc   = in_sizes[0] / 64;
  const int Ncol = in_sizes[1] / 128;
  const int E    = in_sizes[2] / 2;
  const int N    = Nc + Ncol;
  const int E1   = E + N;

  char* p = (char*)d_ws;
  size_t off = 0;
  auto alloc = [&](size_t nbytes) -> void* {
    void* r = p + off;
    off = (off + nbytes + 255) & ~(size_t)255;
    return r;
  };
  unsigned short* Wn_b  = (unsigned short*)alloc(2ull * 256 * 64);
  unsigned short* Wc_b  = (unsigned short*)alloc(2ull * 256 * 128);
  unsigned short* W1b   = (unsigned short*)alloc(2ull * 2048 * 256);
  unsigned short* W2b   = (unsigned short*)alloc(2ull * 256 * 2048);
  unsigned short* Woutb = (unsigned short*)alloc(2ull * 128 * 256);
  unsigned short* consb = (unsigned short*)alloc(2ull * (size_t)Nc * 64);
  unsigned short* colsb = (unsigned short*)alloc(2ull * (size_t)Ncol * 128);
  unsigned short* xb    = (unsigned short*)alloc(2ull * (size_t)N * 256);
  float* v_s1 = (float*)alloc(sizeof(float) * 8 * 256);
  float* v_d1 = (float*)alloc(sizeof(float) * 8 * 256);
  float* a_s1 = (float*)alloc(sizeof(float) * (size_t)N * 8);
  float* a_d1 = (float*)alloc(sizeof(float) * (size_t)N * 8);
  int* esrc = (int*)alloc(4ull * E1);
  int* edst = (int*)alloc(4ull * E1);
  int* cnt1 = (int*)alloc(4ull * 2 * N);
  int* cnt2 = cnt1 + N;
  int* indptr1 = (int*)alloc(4ull * (N + 1));
  int* cur1    = (int*)alloc(4ull * N);
  int* indptr2 = (int*)alloc(4ull * (N + 1));
  int* cur2    = (int*)alloc(4ull * N);
  int* nbr1 = (int*)alloc(4ull * E1);
  int* nbr2 = (int*)alloc(4ull * E1);
  float* alpha1 = (float*)alloc(sizeof(float) * 8ull * E1);
  unsigned short* agg = (unsigned short*)alloc(2ull * (size_t)N * 2048);
  unsigned short* x2  = (unsigned short*)alloc(2ull * (size_t)N * 2048);
  unsigned short* h2b = (unsigned short*)alloc(2ull * (size_t)N * 256);
  float* a2buf = (float*)alloc(sizeof(float) * 2ull * N);   // a_s2 | a_d2 (zeroed)
  float* a_s2 = a2buf;
  float* a_d2 = a2buf + N;
  unsigned short* x3 = (unsigned short*)alloc(2ull * (size_t)Ncol * 256);

  hipMemsetAsync(cnt1, 0, 4ull * 2 * N, stream);
  hipMemsetAsync(a2buf, 0, sizeof(float) * 2ull * N, stream);
  prep<<<1024, 256, 0, stream>>>(W_node, W_col, W1, W2, W_out, constraints, columns,
                                 att_src1, att_dst1,
                                 Wn_b, Wc_b, W1b, W2b, Woutb, consb, colsb,
                                 v_s1, v_d1, Nc * 64, Ncol * 128);

  // encoder (MFMA, bf16 -> xb)
  gemm_mfma_bt<true, true, true, false><<<dim3(2, (Nc + 127) / 128), 512, 0, stream>>>(
      consb, Wn_b, b_node, xb, Nc, 64, 256, 64);
  gemm_mfma_bt<true, true, true, false><<<dim3(2, (Ncol + 127) / 128), 512, 0, stream>>>(
      colsb, Wc_b, b_col, xb + (size_t)Nc * 256, Ncol, 128, 256, 128);

  // attention logits for conv1
  a1_dots<<<(N + 255) / 256, 256, 0, stream>>>(xb, v_s1, v_d1, a_s1, a_d1, N);

  // graph CSR (both directions, neighbor ids stored directly)
  build_count<<<(E1 + 255) / 256, 256, 0, stream>>>(edges, E, N, esrc, edst, cnt1, cnt2, E1);
  scan2_kernel<<<1, 1024, 0, stream>>>(cnt1, indptr1, cur1, cnt2, indptr2, cur2, N);
  scatter_edges<<<(E1 + 255) / 256, 256, 0, stream>>>(esrc, edst, cur1, cur2, nbr1, nbr2, E1);

  // conv1: alphas (thread-per-dst), lean aggregation, block-diag projection
  alpha1_kernel<<<(N + 255) / 256, 256, 0, stream>>>(a_s1, a_d1, indptr1, nbr1, alpha1, N);
  agg1_kernel<<<(N + 3) / 4, 256, 0, stream>>>(xb, alpha1, indptr1, nbr1, agg, N);
  gemm_mfma_bt<true, true, true, true><<<dim3(16, (N + 127) / 128), 512, 0, stream>>>(
      agg, W1b, b1, x2, N, 256, 2048, 2048);

  // conv2: double-buffered projection (+partial att dots via atomics),
  // then fused-alpha aggregation over column nodes
  gemm_k2048_db<<<dim3(2, (N + 31) / 32), 512, 0, stream>>>(
      x2, W2b, h2b, att_src2, att_dst2, a_s2, a_d2, N, 2048);
  agg2_fused<<<(Ncol + 3) / 4, 256, 0, stream>>>(h2b, a_s2, a_d2, indptr2, nbr2, b2, x3,
                                                 Nc, Ncol);

  // output projection -> d_out f32
  gemm_mfma_bt<false, true, false, false><<<dim3(1, (Ncol + 127) / 128), 512, 0, stream>>>(
      x3, Woutb, b_out, (float*)d_out, Ncol, 256, 128, 256);
}

// Round 13
// 366.719 us; speedup vs baseline: 1.0384x; 1.0384x over previous
//
#include <hip/hip_runtime.h>

// ---------------------------------------------------------------------------
// GAT 2-layer forward on MI355X. Round 13 (consolidation):
//  - conv2 projection: REVERT to round-11 single-buffered gemm_mfma_k2048
//    (round-12 double-buffer split columns -> A read twice, FETCH 44->84MB,
//    48->55us. Pipelining cost more HBM than it hid latency.)
//  - KEEP round-12 agg2_fused (alpha2 folded into conv2 aggregation).
//  Everything else = round 11 (best known: 375.9us).
// ---------------------------------------------------------------------------

#define NEG_SLOPE 0.2f

typedef __attribute__((ext_vector_type(8))) short bf16x8;
typedef __attribute__((ext_vector_type(4))) float f32x4;

__device__ __forceinline__ float bf2f(unsigned short u) {
  return __uint_as_float(((unsigned)u) << 16);
}
__device__ __forceinline__ unsigned short f2bf(float f) {
  unsigned u = __float_as_uint(f);
  u += 0x7fffu + ((u >> 16) & 1u);   // round-to-nearest-even
  return (unsigned short)(u >> 16);
}

__device__ __forceinline__ void async_copy16(const void* g, void* l) {
  __builtin_amdgcn_global_load_lds(
      (const __attribute__((address_space(1))) unsigned int*)g,
      (__attribute__((address_space(3))) unsigned int*)l, 16, 0, 0);
}

// ---------------------------------------------------------------------------
// prep: fold W_node/W_col halves, convert MFMA operands to bf16, and compute
// v_s1/v_d1 = att1 @ W1 (per-head 256-dots) as an extra index range.
__global__ void prep(const float* __restrict__ Wn, const float* __restrict__ Wc,
                     const float* __restrict__ W1, const float* __restrict__ W2,
                     const float* __restrict__ Wout,
                     const float* __restrict__ cons, const float* __restrict__ cols,
                     const float* __restrict__ att_s1, const float* __restrict__ att_d1,
                     unsigned short* __restrict__ Wn_b, unsigned short* __restrict__ Wc_b,
                     unsigned short* __restrict__ W1b, unsigned short* __restrict__ W2b,
                     unsigned short* __restrict__ Woutb,
                     unsigned short* __restrict__ consb, unsigned short* __restrict__ colsb,
                     float* __restrict__ v_s1, float* __restrict__ v_d1,
                     int n_cons, int n_cols) {
  const int S0 = 256 * 64;
  const int S1 = 256 * 128;
  const int S2 = 2048 * 256;
  const int S3 = 256 * 2048;
  const int S4 = 128 * 256;
  const int S5 = 2048;                 // v1 (h,k) items
  int total = S0 + S1 + S2 + S3 + S4 + n_cons + n_cols + S5;
  for (int idx = blockIdx.x * 256 + threadIdx.x; idx < total; idx += gridDim.x * 256) {
    int i = idx;
    if (i < S0) { int o = i >> 6, j = i & 63;
      Wn_b[i] = f2bf(Wn[o * 128 + j] + Wn[o * 128 + 64 + j]); continue; }
    i -= S0;
    if (i < S1) { int o = i >> 7, j = i & 127;
      Wc_b[i] = f2bf(Wc[o * 256 + j] + Wc[o * 256 + 128 + j]); continue; }
    i -= S1;
    if (i < S2) { W1b[i] = f2bf(W1[i]); continue; }
    i -= S2;
    if (i < S3) { W2b[i] = f2bf(W2[i]); continue; }
    i -= S3;
    if (i < S4) { Woutb[i] = f2bf(Wout[i]); continue; }
    i -= S4;
    if (i < n_cons) { consb[i] = f2bf(cons[i]); continue; }
    i -= n_cons;
    if (i < n_cols) { colsb[i] = f2bf(cols[i]); continue; }
    i -= n_cols;
    { // v1: i in [0,2048), h = i>>8, k = i&255
      int h = i >> 8, k = i & 255;
      const float* Wrow = W1 + (size_t)h * 256 * 256 + k;
      const float* as = att_s1 + h * 256;
      const float* ad = att_d1 + h * 256;
      float s = 0.f, d = 0.f;
      for (int c = 0; c < 256; ++c) {
        float w = Wrow[(size_t)c * 256];
        s += as[c] * w;
        d += ad[c] * w;
      }
      v_s1[i] = s; v_d1[i] = d;
    }
  }
}

// ---------------------------------------------------------------------------
// a_s1[n,h] = xb[n,:] . v_s[h,:]  (thread per node; v in LDS, broadcast reads)
__global__ __launch_bounds__(256) void a1_dots(const unsigned short* __restrict__ xb,
                                               const float* __restrict__ v_s,
                                               const float* __restrict__ v_d,
                                               float* __restrict__ a_s,
                                               float* __restrict__ a_d, int N) {
  __shared__ float vs[2048], vd[2048];
  for (int i = threadIdx.x; i < 2048; i += 256) { vs[i] = v_s[i]; vd[i] = v_d[i]; }
  __syncthreads();
  int n = blockIdx.x * 256 + threadIdx.x;
  if (n >= N) return;
  const unsigned short* row = xb + (size_t)n * 256;
  float s[8] = {}, d[8] = {};
  for (int c = 0; c < 256; c += 8) {
    bf16x8 xv = *(const bf16x8*)(row + c);
    float xf[8];
#pragma unroll
    for (int i = 0; i < 8; ++i) xf[i] = bf2f(((const unsigned short*)&xv)[i]);
#pragma unroll
    for (int h = 0; h < 8; ++h)
#pragma unroll
      for (int i = 0; i < 8; ++i) {
        s[h] += xf[i] * vs[h * 256 + c + i];
        d[h] += xf[i] * vd[h * 256 + c + i];
      }
  }
#pragma unroll
  for (int h = 0; h < 8; ++h) { a_s[n * 8 + h] = s[h]; a_d[n * 8 + h] = d[h]; }
}

// ---------------------------------------------------------------------------
// bf16 MFMA GEMM, B^T layout: C[m,n] = sum_k A[m, koff+k] * W[n,k] (+bias,relu).
// 512 threads, 8 waves; wave w owns rows [(w&3)*32,+32) x cols [(w>>2)*64,+64)
// of the 128x128 tile. XOR-swizzled staging, coalesced bf16 epilogue via LDS.
template <bool C_BF16, bool BIAS, bool RELU, bool BDIAG>
__global__ __launch_bounds__(512) void gemm_mfma_bt(const unsigned short* __restrict__ A,
                                                    const unsigned short* __restrict__ W,
                                                    const float* __restrict__ bias,
                                                    void* __restrict__ Cv,
                                                    int M, int K, int Nout, int lda) {
  __shared__ short smem[2 * 128 * 64];   // sA | sB, reused as C-tile in epilogue
  short* sA = smem;
  short* sB = smem + 128 * 64;
  float* Cf = (float*)Cv;
  unsigned short* Cb = (unsigned short*)Cv;

  const int tid = threadIdx.x;
  const int lane = tid & 63, w = tid >> 6;
  const int m0 = blockIdx.y * 128, n0 = blockIdx.x * 128;
  const int koff = BDIAG ? (n0 >> 8) << 8 : 0;
  const int wm = (w & 3) * 32, wn = (w >> 2) * 64;
  const int fr = lane & 15;
  const int frs = fr & 7;
  const int quad = lane >> 4;

  f32x4 acc[2][4];
#pragma unroll
  for (int i = 0; i < 2; ++i)
#pragma unroll
    for (int j = 0; j < 4; ++j) acc[i][j] = (f32x4){0.f, 0.f, 0.f, 0.f};

  for (int k0 = 0; k0 < K; k0 += 64) {
#pragma unroll
    for (int i = 0; i < 2; ++i) {
      int c = i * 512 + tid;
      int row = c >> 3, kc = c & 7;
      int kcs = kc ^ (row & 7);            // XOR swizzle (global side)
      int grow = m0 + row;
      if (grow >= M) grow = M - 1;
      async_copy16(A + (size_t)grow * lda + koff + k0 + kcs * 8, &sA[(i * 512 + w * 64) * 8]);
    }
#pragma unroll
    for (int i = 0; i < 2; ++i) {
      int c = i * 512 + tid;
      int row = c >> 3, kc = c & 7;
      int kcs = kc ^ (row & 7);
      async_copy16(W + (size_t)(n0 + row) * K + k0 + kcs * 8, &sB[(i * 512 + w * 64) * 8]);
    }
    __syncthreads();

#pragma unroll
    for (int ks = 0; ks < 2; ++ks) {
      bf16x8 af[2], bfr[4];
#pragma unroll
      for (int mi = 0; mi < 2; ++mi) {
        int row = wm + mi * 16 + fr;
        af[mi] = *(const bf16x8*)&sA[(row * 8 + ((ks * 4 + quad) ^ frs)) * 8];
      }
#pragma unroll
      for (int ni = 0; ni < 4; ++ni) {
        int row = wn + ni * 16 + fr;
        bfr[ni] = *(const bf16x8*)&sB[(row * 8 + ((ks * 4 + quad) ^ frs)) * 8];
      }
#pragma unroll
      for (int mi = 0; mi < 2; ++mi)
#pragma unroll
        for (int ni = 0; ni < 4; ++ni)
          acc[mi][ni] = __builtin_amdgcn_mfma_f32_16x16x32_bf16(
              af[mi], bfr[ni], acc[mi][ni], 0, 0, 0);
    }
    __syncthreads();
  }

  if (C_BF16) {
    unsigned short* hsh = (unsigned short*)smem;    // 128*128 u16 = 32 KB
#pragma unroll
    for (int mi = 0; mi < 2; ++mi)
#pragma unroll
      for (int ni = 0; ni < 4; ++ni) {
        int col = wn + ni * 16 + fr;
        float bv = BIAS ? bias[n0 + col] : 0.f;
        f32x4 v = acc[mi][ni];
#pragma unroll
        for (int r = 0; r < 4; ++r) {
          int row = wm + mi * 16 + quad * 4 + r;
          float x = v[r] + bv;
          if (RELU) x = fmaxf(x, 0.f);
          hsh[row * 128 + (col ^ (((row >> 2) & 3) << 5))] = f2bf(x);
        }
      }
    __syncthreads();
#pragma unroll
    for (int i = 0; i < 4; ++i) {
      int slot = i * 512 + tid;          // 0..2047 = 128 rows x 16 col-groups
      int row = slot >> 4, cg = slot & 15;
      int colbase = cg * 8;
      bf16x8 val = *(const bf16x8*)&hsh[row * 128 + (colbase ^ (((row >> 2) & 3) << 5))];
      int grow = m0 + row;
      if (grow < M)
        *(bf16x8*)(Cb + (size_t)grow * Nout + n0 + colbase) = val;
    }
  } else {
#pragma unroll
    for (int mi = 0; mi < 2; ++mi)
#pragma unroll
      for (int ni = 0; ni < 4; ++ni) {
        int col = n0 + wn + ni * 16 + fr;
        float bv = BIAS ? bias[col] : 0.f;
        f32x4 v = acc[mi][ni];
#pragma unroll
        for (int r = 0; r < 4; ++r) {
          int row = m0 + wm + mi * 16 + quad * 4 + r;
          if (row < M) {
            float x = v[r] + bv;
            if (RELU) x = fmaxf(x, 0.f);
            Cf[(size_t)row * Nout + col] = x;
          }
        }
      }
  }
}

// ---------------------------------------------------------------------------
// conv2 projection GEMM: h2[M,256] = A[M,2048] * W[256,2048]^T, bf16 out,
// PLUS fused attention dots. Tile 32x256, grid = M/32 blocks.
// 512 threads / 8 waves: wave w owns cols [w*32,+32) -> acc 2x2 = 16 AGPR.
// LDS tiles XOR-swizzled (round-11 proven version).
__global__ __launch_bounds__(512) void gemm_mfma_k2048(const unsigned short* __restrict__ A,
                                                       const unsigned short* __restrict__ W,
                                                       unsigned short* __restrict__ C,
                                                       const float* __restrict__ att_s,
                                                       const float* __restrict__ att_d,
                                                       float* __restrict__ a_s,
                                                       float* __restrict__ a_d,
                                                       int M, int K) {
  __shared__ short sA[32 * 64];
  __shared__ short sB[256 * 64];
  const int tid = threadIdx.x;
  const int lane = tid & 63, w = tid >> 6;   // w in 0..7
  const int m0 = blockIdx.x * 32;
  const int fr = lane & 15, quad = lane >> 4;
  const int frs = fr & 7;

  f32x4 acc[2][2];
#pragma unroll
  for (int i = 0; i < 2; ++i)
#pragma unroll
    for (int j = 0; j < 2; ++j) acc[i][j] = (f32x4){0.f, 0.f, 0.f, 0.f};

  for (int k0 = 0; k0 < K; k0 += 64) {
    if (w < 4) {  // A tile: 32x64 = 256 chunks, waves 0..3 (wave-uniform base)
      int row = tid >> 3, kc = tid & 7;
      int kcs = kc ^ (row & 7);
      int grow = m0 + row;
      if (grow >= M) grow = M - 1;
      async_copy16(A + (size_t)grow * K + k0 + kcs * 8, &sA[(w * 64) * 8]);
    }
#pragma unroll
    for (int i = 0; i < 4; ++i) {  // B tile: 256x64 = 2048 chunks
      int c = i * 512 + tid;
      int row = c >> 3, kc = c & 7;
      int kcs = kc ^ (row & 7);
      async_copy16(W + (size_t)row * K + k0 + kcs * 8, &sB[(i * 512 + w * 64) * 8]);
    }
    __syncthreads();

#pragma unroll
    for (int ks = 0; ks < 2; ++ks) {
      bf16x8 af[2], bfr[2];
#pragma unroll
      for (int mi = 0; mi < 2; ++mi) {
        int row = mi * 16 + fr;
        af[mi] = *(const bf16x8*)&sA[(row * 8 + ((ks * 4 + quad) ^ frs)) * 8];
      }
#pragma unroll
      for (int ni = 0; ni < 2; ++ni) {
        int row = w * 32 + ni * 16 + fr;
        bfr[ni] = *(const bf16x8*)&sB[(row * 8 + ((ks * 4 + quad) ^ frs)) * 8];
      }
#pragma unroll
      for (int mi = 0; mi < 2; ++mi)
#pragma unroll
        for (int ni = 0; ni < 2; ++ni)
          acc[mi][ni] = __builtin_amdgcn_mfma_f32_16x16x32_bf16(
              af[mi], bfr[ni], acc[mi][ni], 0, 0, 0);
    }
    __syncthreads();
  }

  // epilogue: stage tile in LDS, then coalesced h2 stores + fused att dots
  unsigned short* hsh = (unsigned short*)sB;   // 32x256 u16 = 16KB (sB is 32KB)
#pragma unroll
  for (int mi = 0; mi < 2; ++mi)
#pragma unroll
    for (int ni = 0; ni < 2; ++ni) {
      int col = w * 32 + ni * 16 + fr;
      f32x4 v = acc[mi][ni];
#pragma unroll
      for (int r = 0; r < 4; ++r) {
        int rl = mi * 16 + quad * 4 + r;
        hsh[rl * 256 + col] = f2bf(v[r]);
      }
    }
  __syncthreads();

  // coalesced h2 stores: 32 rows x 32 col-groups = 1024 slots, 2 per thread
#pragma unroll
  for (int i = 0; i < 2; ++i) {
    int slot = i * 512 + tid;
    int row = slot >> 5, cg = slot & 31;
    int grow = m0 + row;
    if (grow < M)
      *(bf16x8*)(C + (size_t)grow * 256 + cg * 8) = *(const bf16x8*)&hsh[row * 256 + cg * 8];
  }

  // dots: 16 threads per row, 16 cols each, shfl-reduce within 16-lane group
  int r = tid >> 4;
  int cbase = (tid & 15) * 16;
  float s = 0.f, d = 0.f;
#pragma unroll
  for (int q = 0; q < 2; ++q) {
    bf16x8 hv8 = *(const bf16x8*)&hsh[r * 256 + cbase + q * 8];
    const unsigned short* hp = (const unsigned short*)&hv8;
#pragma unroll
    for (int i = 0; i < 8; ++i) {
      int c = cbase + q * 8 + i;
      float hv = bf2f(hp[i]);
      s += hv * att_s[c];
      d += hv * att_d[c];
    }
  }
#pragma unroll
  for (int off = 8; off; off >>= 1) {
    s += __shfl_down(s, off);
    d += __shfl_down(d, off);
  }
  if ((tid & 15) == 0 && m0 + r < M) {
    a_s[m0 + r] = s;
    a_d[m0 + r] = d;
  }
}

// ---------------------------------------------------------------------------
// Edge materialization + degree counts (fused). int64/int32 auto-detect.
__global__ void build_count(const void* __restrict__ edges_raw, int E, int N,
                            int* __restrict__ esrc, int* __restrict__ edst,
                            int* __restrict__ cnt1, int* __restrict__ cnt2, int E1) {
  const long long* p64 = (const long long*)edges_raw;
  const int* p32 = (const int*)edges_raw;
  bool is64 = true;
#pragma unroll
  for (int i = 0; i < 8; ++i) {
    long long v = p64[i];
    if (v < 0 || v >= N) is64 = false;
  }
  int idx = blockIdx.x * 256 + threadIdx.x;
  if (idx >= E1) return;
  int s, d;
  if (idx < E) {
    if (is64) { s = (int)p64[idx]; d = (int)p64[E + idx]; }
    else      { s = p32[idx];      d = p32[E + idx]; }
  } else {
    s = d = idx - E;
  }
  esrc[idx] = s;
  edst[idx] = d;
  atomicAdd(&cnt1[d], 1);
  atomicAdd(&cnt2[s], 1);
}

// ---------------------------------------------------------------------------
// Shuffle-based single-block scan: 3 barriers per 1024-chunk.
__device__ __forceinline__ void scan_one(const int* __restrict__ cnt,
                                         int* __restrict__ indptr,
                                         int* __restrict__ cur, int N, int* buf) {
  int t = threadIdx.x, lane = t & 63, w = t >> 6;
  int running = 0;
  for (int base = 0; base < N; base += 1024) {
    int v = (base + t < N) ? cnt[base + t] : 0;
    int incl = v;
#pragma unroll
    for (int off = 1; off < 64; off <<= 1) {
      int y = __shfl_up(incl, off);
      if (lane >= off) incl += y;
    }
    if (lane == 63) buf[w] = incl;
    __syncthreads();
    if (t < 16) {
      int x = buf[t];
#pragma unroll
      for (int off = 1; off < 16; off <<= 1) {
        int y = __shfl_up(x, off);
        if (t >= off) x += y;
      }
      buf[t] = x;
    }
    __syncthreads();
    int woff = w ? buf[w - 1] : 0;
    int tot = buf[15];
    if (base + t < N) {
      int excl = running + woff + incl - v;
      indptr[base + t] = excl;
      cur[base + t] = excl;
    }
    running += tot;
    __syncthreads();
  }
  if (t == 0) indptr[N] = running;
  __syncthreads();
}

__global__ __launch_bounds__(1024) void scan2_kernel(const int* cnt1, int* indptr1, int* cur1,
                                                     const int* cnt2, int* indptr2, int* cur2,
                                                     int N) {
  __shared__ int buf[16];
  scan_one(cnt1, indptr1, cur1, N, buf);
  scan_one(cnt2, indptr2, cur2, N, buf);
}

// scatter neighbor node-ids directly.
__global__ void scatter_edges(const int* __restrict__ esrc, const int* __restrict__ edst,
                              int* __restrict__ cur1, int* __restrict__ cur2,
                              int* __restrict__ nbr1, int* __restrict__ nbr2, int E1) {
  int e = blockIdx.x * 256 + threadIdx.x;
  if (e >= E1) return;
  int s = esrc[e], d = edst[e];
  int p1 = atomicAdd(&cur1[d], 1);
  nbr1[p1] = s;
  int p2 = atomicAdd(&cur2[s], 1);
  nbr2[p2] = d;
}

// ---------------------------------------------------------------------------
// alpha1: thread-per-dst scalar online softmax (8 heads); writes NORMALIZED
// alpha to CSR slots [slot*8+h].
__global__ __launch_bounds__(256) void alpha1_kernel(const float* __restrict__ a_s,
                                                     const float* __restrict__ a_d,
                                                     const int* __restrict__ indptr,
                                                     const int* __restrict__ nbr,
                                                     float* __restrict__ alpha, int N) {
  int n = blockIdx.x * 256 + threadIdx.x;
  if (n >= N) return;
  int start = indptr[n], end = indptr[n + 1];
  float ad[8];
  *(float4*)&ad[0] = *(const float4*)&a_d[n * 8];
  *(float4*)&ad[4] = *(const float4*)&a_d[n * 8 + 4];
  float m[8], ssum[8];
#pragma unroll
  for (int h = 0; h < 8; ++h) { m[h] = -1e30f; ssum[h] = 0.f; }
  for (int p = start; p < end; ++p) {
    int s = nbr[p];
    float as[8];
    *(float4*)&as[0] = *(const float4*)&a_s[s * 8];
    *(float4*)&as[4] = *(const float4*)&a_s[s * 8 + 4];
#pragma unroll
    for (int h = 0; h < 8; ++h) {
      float e = as[h] + ad[h];
      e = e > 0.f ? e : NEG_SLOPE * e;
      float nm = fmaxf(m[h], e);
      ssum[h] = ssum[h] * __expf(m[h] - nm) + __expf(e - nm);
      m[h] = nm;
    }
  }
  float inv[8];
#pragma unroll
  for (int h = 0; h < 8; ++h) inv[h] = 1.f / (ssum[h] + 1e-16f);
  for (int p = start; p < end; ++p) {
    int s = nbr[p];
    float as[8];
    *(float4*)&as[0] = *(const float4*)&a_s[s * 8];
    *(float4*)&as[4] = *(const float4*)&a_s[s * 8 + 4];
    float av[8];
#pragma unroll
    for (int h = 0; h < 8; ++h) {
      float e = as[h] + ad[h];
      e = e > 0.f ? e : NEG_SLOPE * e;
      av[h] = __expf(e - m[h]) * inv[h];
    }
    *(float4*)&alpha[(size_t)p * 8] = *(const float4*)&av[0];
    *(float4*)&alpha[(size_t)p * 8 + 4] = *(const float4*)&av[4];
  }
}

// ---------------------------------------------------------------------------
// conv1 aggregation, lean: wave-per-dst (4/block), alphas precomputed.
__global__ __launch_bounds__(256) void agg1_kernel(const unsigned short* __restrict__ xb,
                                                   const float* __restrict__ alpha,
                                                   const int* __restrict__ indptr,
                                                   const int* __restrict__ nbr,
                                                   unsigned short* __restrict__ agg,
                                                   int N) {
  __shared__ float al_sh[4][64 * 8];
  const int w = threadIdx.x >> 6, lane = threadIdx.x & 63;
  const int dst = blockIdx.x * 4 + w;
  if (dst >= N) return;
  const int start = indptr[dst];
  const int deg = indptr[dst + 1] - start;
  const int c0 = lane * 4;

  float acc[8][4];
#pragma unroll
  for (int h = 0; h < 8; ++h)
#pragma unroll
    for (int i = 0; i < 4; ++i) acc[h][i] = 0.f;

  for (int base = 0; base < deg; base += 64) {
    int cnt = min(64, deg - base);
    int s = 0;
    if (lane < cnt) {
      int slot = start + base + lane;
      s = nbr[slot];
      f32x4 a0 = *(const f32x4*)&alpha[(size_t)slot * 8];
      f32x4 a1 = *(const f32x4*)&alpha[(size_t)slot * 8 + 4];
      *(f32x4*)&al_sh[w][lane * 8] = a0;
      *(f32x4*)&al_sh[w][lane * 8 + 4] = a1;
    }
    __builtin_amdgcn_wave_barrier();
    for (int j = 0; j < cnt; ++j) {
      int sj = __shfl(s, j);
      f32x4 alo = *(const f32x4*)&al_sh[w][j * 8];
      f32x4 ahi = *(const f32x4*)&al_sh[w][j * 8 + 4];
      ushort4 xv = *(const ushort4*)(xb + (size_t)sj * 256 + c0);
      float x0 = bf2f(xv.x), x1 = bf2f(xv.y), x2 = bf2f(xv.z), x3 = bf2f(xv.w);
#pragma unroll
      for (int h = 0; h < 4; ++h) {
        acc[h][0] += alo[h] * x0; acc[h][1] += alo[h] * x1;
        acc[h][2] += alo[h] * x2; acc[h][3] += alo[h] * x3;
      }
#pragma unroll
      for (int h = 0; h < 4; ++h) {
        acc[h + 4][0] += ahi[h] * x0; acc[h + 4][1] += ahi[h] * x1;
        acc[h + 4][2] += ahi[h] * x2; acc[h + 4][3] += ahi[h] * x3;
      }
    }
    __builtin_amdgcn_wave_barrier();
  }

  unsigned short* op = agg + (size_t)dst * 2048;
#pragma unroll
  for (int h = 0; h < 8; ++h) {
    unsigned short ov[4];
#pragma unroll
    for (int i = 0; i < 4; ++i) ov[i] = f2bf(acc[h][i]);
    *((ushort4*)(op + h * 256 + c0)) = *((const ushort4*)ov);
  }
}

// ---------------------------------------------------------------------------
// conv2 aggregation with FUSED online-softmax alpha (1 head), wave-per-dst,
// dst in [Nc,N) only.
__global__ __launch_bounds__(256) void agg2_fused(const unsigned short* __restrict__ h2,
                                                  const float* __restrict__ a_s,
                                                  const float* __restrict__ a_d,
                                                  const int* __restrict__ indptr,
                                                  const int* __restrict__ nbr,
                                                  const float* __restrict__ b2,
                                                  unsigned short* __restrict__ x3,
                                                  int Nc, int Ncol) {
  const int w = threadIdx.x >> 6, lane = threadIdx.x & 63;
  const int i0 = blockIdx.x * 4 + w;
  if (i0 >= Ncol) return;
  const int dst = Nc + i0;
  const int start = indptr[dst];
  const int deg = indptr[dst + 1] - start;
  const float ad = a_d[dst];
  float run_m = -1e30f, run_s = 0.f;
  float acc[4] = {0.f, 0.f, 0.f, 0.f};
  const int c0 = lane * 4;

  for (int base = 0; base < deg; base += 64) {
    int cnt = min(64, deg - base);
    float ev = -1e30f;
    int s = 0;
    if (lane < cnt) {
      s = nbr[start + base + lane];
      float e = a_s[s] + ad;
      ev = e > 0.f ? e : NEG_SLOPE * e;
    }
    float cm = ev;
#pragma unroll
    for (int off = 32; off; off >>= 1) cm = fmaxf(cm, __shfl_xor(cm, off));
    float nm = fmaxf(run_m, cm);
    float sc = __expf(run_m - nm);
    float e = (lane < cnt) ? __expf(ev - nm) : 0.f;
    float cs = e;
#pragma unroll
    for (int off = 32; off; off >>= 1) cs += __shfl_xor(cs, off);
    run_s = run_s * sc + cs;
    run_m = nm;
#pragma unroll
    for (int i = 0; i < 4; ++i) acc[i] *= sc;
    for (int j = 0; j < cnt; ++j) {
      int sj = __shfl(s, j);
      float al = __shfl(e, j);
      ushort4 hv = *(const ushort4*)(h2 + (size_t)sj * 256 + c0);
      acc[0] += al * bf2f(hv.x);
      acc[1] += al * bf2f(hv.y);
      acc[2] += al * bf2f(hv.z);
      acc[3] += al * bf2f(hv.w);
    }
  }

  float inv = 1.f / (run_s + 1e-16f);
  float4 bv = *(const float4*)&b2[c0];
  unsigned short ov[4];
  ov[0] = f2bf(fmaxf(acc[0] * inv + bv.x, 0.f));
  ov[1] = f2bf(fmaxf(acc[1] * inv + bv.y, 0.f));
  ov[2] = f2bf(fmaxf(acc[2] * inv + bv.z, 0.f));
  ov[3] = f2bf(fmaxf(acc[3] * inv + bv.w, 0.f));
  *((ushort4*)(x3 + (size_t)i0 * 256 + c0)) = *((const ushort4*)ov);
}

// ---------------------------------------------------------------------------
extern "C" void kernel_launch(void* const* d_in, const int* in_sizes, int n_in,
                              void* d_out, int out_size, void* d_ws, size_t ws_size,
                              hipStream_t stream) {
  (void)n_in; (void)out_size; (void)ws_size;
  const float* constraints = (const float*)d_in[0];
  const float* columns     = (const float*)d_in[1];
  const void*  edges       = d_in[2];
  const float* W_node = (const float*)d_in[3];
  const float* b_node = (const float*)d_in[4];
  const float* W_col  = (const float*)d_in[5];
  const float* b_col  = (const float*)d_in[6];
  const float* W1       = (const float*)d_in[7];
  const float* att_src1 = (const float*)d_in[8];
  const float* att_dst1 = (const float*)d_in[9];
  const float* b1       = (const float*)d_in[10];
  const float* W2       = (const float*)d_in[11];
  const float* att_src2 = (const float*)d_in[12];
  const float* att_dst2 = (const float*)d_in[13];
  const float* b2       = (const float*)d_in[14];
  const float* W_out    = (const float*)d_in[15];
  const float* b_out    = (const float*)d_in[16];

  const int Nc   = in_sizes[0] / 64;
  const int Ncol = in_sizes[1] / 128;
  const int E    = in_sizes[2] / 2;
  const int N    = Nc + Ncol;
  const int E1   = E + N;

  char* p = (char*)d_ws;
  size_t off = 0;
  auto alloc = [&](size_t nbytes) -> void* {
    void* r = p + off;
    off = (off + nbytes + 255) & ~(size_t)255;
    return r;
  };
  unsigned short* Wn_b  = (unsigned short*)alloc(2ull * 256 * 64);
  unsigned short* Wc_b  = (unsigned short*)alloc(2ull * 256 * 128);
  unsigned short* W1b   = (unsigned short*)alloc(2ull * 2048 * 256);
  unsigned short* W2b   = (unsigned short*)alloc(2ull * 256 * 2048);
  unsigned short* Woutb = (unsigned short*)alloc(2ull * 128 * 256);
  unsigned short* consb = (unsigned short*)alloc(2ull * (size_t)Nc * 64);
  unsigned short* colsb = (unsigned short*)alloc(2ull * (size_t)Ncol * 128);
  unsigned short* xb    = (unsigned short*)alloc(2ull * (size_t)N * 256);
  float* v_s1 = (float*)alloc(sizeof(float) * 8 * 256);
  float* v_d1 = (float*)alloc(sizeof(float) * 8 * 256);
  float* a_s1 = (float*)alloc(sizeof(float) * (size_t)N * 8);
  float* a_d1 = (float*)alloc(sizeof(float) * (size_t)N * 8);
  int* esrc = (int*)alloc(4ull * E1);
  int* edst = (int*)alloc(4ull * E1);
  int* cnt1 = (int*)alloc(4ull * 2 * N);
  int* cnt2 = cnt1 + N;
  int* indptr1 = (int*)alloc(4ull * (N + 1));
  int* cur1    = (int*)alloc(4ull * N);
  int* indptr2 = (int*)alloc(4ull * (N + 1));
  int* cur2    = (int*)alloc(4ull * N);
  int* nbr1 = (int*)alloc(4ull * E1);
  int* nbr2 = (int*)alloc(4ull * E1);
  float* alpha1 = (float*)alloc(sizeof(float) * 8ull * E1);
  unsigned short* agg = (unsigned short*)alloc(2ull * (size_t)N * 2048);
  unsigned short* x2  = (unsigned short*)alloc(2ull * (size_t)N * 2048);
  unsigned short* h2b = (unsigned short*)alloc(2ull * (size_t)N * 256);
  float* a_s2 = (float*)alloc(sizeof(float) * (size_t)N);
  float* a_d2 = (float*)alloc(sizeof(float) * (size_t)N);
  unsigned short* x3 = (unsigned short*)alloc(2ull * (size_t)Ncol * 256);

  hipMemsetAsync(cnt1, 0, 4ull * 2 * N, stream);
  prep<<<1024, 256, 0, stream>>>(W_node, W_col, W1, W2, W_out, constraints, columns,
                                 att_src1, att_dst1,
                                 Wn_b, Wc_b, W1b, W2b, Woutb, consb, colsb,
                                 v_s1, v_d1, Nc * 64, Ncol * 128);

  // encoder (MFMA, bf16 -> xb)
  gemm_mfma_bt<true, true, true, false><<<dim3(2, (Nc + 127) / 128), 512, 0, stream>>>(
      consb, Wn_b, b_node, xb, Nc, 64, 256, 64);
  gemm_mfma_bt<true, true, true, false><<<dim3(2, (Ncol + 127) / 128), 512, 0, stream>>>(
      colsb, Wc_b, b_col, xb + (size_t)Nc * 256, Ncol, 128, 256, 128);

  // attention logits for conv1
  a1_dots<<<(N + 255) / 256, 256, 0, stream>>>(xb, v_s1, v_d1, a_s1, a_d1, N);

  // graph CSR (both directions, neighbor ids stored directly)
  build_count<<<(E1 + 255) / 256, 256, 0, stream>>>(edges, E, N, esrc, edst, cnt1, cnt2, E1);
  scan2_kernel<<<1, 1024, 0, stream>>>(cnt1, indptr1, cur1, cnt2, indptr2, cur2, N);
  scatter_edges<<<(E1 + 255) / 256, 256, 0, stream>>>(esrc, edst, cur1, cur2, nbr1, nbr2, E1);

  // conv1: alphas (thread-per-dst), lean aggregation, block-diag projection
  alpha1_kernel<<<(N + 255) / 256, 256, 0, stream>>>(a_s1, a_d1, indptr1, nbr1, alpha1, N);
  agg1_kernel<<<(N + 3) / 4, 256, 0, stream>>>(xb, alpha1, indptr1, nbr1, agg, N);
  gemm_mfma_bt<true, true, true, true><<<dim3(16, (N + 127) / 128), 512, 0, stream>>>(
      agg, W1b, b1, x2, N, 256, 2048, 2048);

  // conv2: projection with fused full-row att dots, then fused-alpha
  // aggregation over column nodes
  gemm_mfma_k2048<<<(N + 31) / 32, 512, 0, stream>>>(
      x2, W2b, h2b, att_src2, att_dst2, a_s2, a_d2, N, 2048);
  agg2_fused<<<(Ncol + 3) / 4, 256, 0, stream>>>(h2b, a_s2, a_d2, indptr2, nbr2, b2, x3,
                                                 Nc, Ncol);

  // output projection -> d_out f32
  gemm_mfma_bt<false, true, false, false><<<dim3(1, (Ncol + 127) / 128), 512, 0, stream>>>(
      x3, Woutb, b_out, (float*)d_out, Ncol, 256, 128, 256);
}